// Round 1
// baseline (934.012 us; speedup 1.0000x reference)
//
#include <hip/hip_runtime.h>

#define H 256
#define NSLOT 4

typedef short bf16x8 __attribute__((ext_vector_type(8)));
typedef float f32x4  __attribute__((ext_vector_type(4)));

__device__ __forceinline__ unsigned int f2bf(float f) {
    unsigned int u = __float_as_uint(f);
    return (u + 0x7fffu + ((u >> 16) & 1u)) >> 16;   // RNE to bf16
}

__global__ void conv_w_kernel(const float* __restrict__ W1, const float* __restrict__ W2,
                              unsigned short* __restrict__ W1b, unsigned short* __restrict__ W2b) {
    int i = blockIdx.x * 256 + threadIdx.x;           // 256 blocks x 256 = 65536
    W1b[i] = (unsigned short)f2bf(W1[i]);
    W2b[i] = (unsigned short)f2bf(W2[i]);
}

// 4 waves/block, 16 rows/wave, 64 rows/block. MFMA 16x16x32 bf16.
// A layout: A[m=lane&15][k=quad*8+j]; B layout: B[k=quad*8+j][n=lane&15];
// C/D: col=lane&15, row=quad*4+reg.
__global__ __launch_bounds__(256, 2) void fused_main(
    const float* __restrict__ x, const int* __restrict__ batch,
    const unsigned short* __restrict__ W1b, const float* __restrict__ b1,
    const unsigned short* __restrict__ W2b, const float* __restrict__ b2,
    float* __restrict__ out, int* __restrict__ counts)
{
    __shared__ __align__(16) unsigned short hlds[4][16][264];  // +8 pad: row stride 528B -> 4-bank skew
    __shared__ float        bsum[NSLOT][H];
    __shared__ unsigned int bmax[NSLOT][H];

    const int tid  = threadIdx.x;
    const int wave = tid >> 6;
    const int lane = tid & 63;
    const int r    = lane & 15;   // m / n index
    const int q    = lane >> 4;   // quad
    const int base = blockIdx.x * 64;
    const int r0   = base + wave * 16;

    for (int i = tid; i < NSLOT * H; i += 256) {
        (&bsum[0][0])[i] = 0.0f;
        (&bmax[0][0])[i] = 0u;
    }

    // ---- GEMM1: h = relu(x @ W1^T + b1) ----
    f32x4 acc[16];
#pragma unroll
    for (int ct = 0; ct < 16; ++ct) acc[ct] = (f32x4){0.f, 0.f, 0.f, 0.f};

    const float* xrow = x + (size_t)(r0 + r) * H;
#pragma unroll
    for (int kk = 0; kk < 8; ++kk) {
        const int k0 = kk * 32 + q * 8;
        const float4 alo = *(const float4*)(xrow + k0);
        const float4 ahi = *(const float4*)(xrow + k0 + 4);
        bf16x8 af;
        af[0] = (short)f2bf(alo.x); af[1] = (short)f2bf(alo.y);
        af[2] = (short)f2bf(alo.z); af[3] = (short)f2bf(alo.w);
        af[4] = (short)f2bf(ahi.x); af[5] = (short)f2bf(ahi.y);
        af[6] = (short)f2bf(ahi.z); af[7] = (short)f2bf(ahi.w);
#pragma unroll
        for (int ct = 0; ct < 16; ++ct) {
            bf16x8 bf = *(const bf16x8*)(W1b + (size_t)(ct * 16 + r) * H + k0);
            acc[ct] = __builtin_amdgcn_mfma_f32_16x16x32_bf16(af, bf, acc[ct], 0, 0, 0);
        }
    }

    f32x4 hv[16];
#pragma unroll
    for (int ct = 0; ct < 16; ++ct) {
        const float bb = b1[ct * 16 + r];
#pragma unroll
        for (int e = 0; e < 4; ++e) {
            float h = acc[ct][e] + bb;
            h = h > 0.f ? h : 0.f;
            hv[ct][e] = h;
            hlds[wave][q * 4 + e][ct * 16 + r] = (unsigned short)f2bf(h);
        }
    }
    __syncthreads();  // covers bsum/bmax zero-init + hlds writes

    // ---- GEMM2: att = sigmoid(h @ W2^T + b2); g = h*att ----
    f32x4 acc2[16];
#pragma unroll
    for (int ct = 0; ct < 16; ++ct) acc2[ct] = (f32x4){0.f, 0.f, 0.f, 0.f};

#pragma unroll
    for (int kk = 0; kk < 8; ++kk) {
        const int k0 = kk * 32 + q * 8;
        bf16x8 af = *(const bf16x8*)(&hlds[wave][r][k0]);
#pragma unroll
        for (int ct = 0; ct < 16; ++ct) {
            bf16x8 bf = *(const bf16x8*)(W2b + (size_t)(ct * 16 + r) * H + k0);
            acc2[ct] = __builtin_amdgcn_mfma_f32_16x16x32_bf16(af, bf, acc2[ct], 0, 0, 0);
        }
    }

#pragma unroll
    for (int ct = 0; ct < 16; ++ct) {
        const float bb = b2[ct * 16 + r];
#pragma unroll
        for (int e = 0; e < 4; ++e) {
            float t   = acc2[ct][e] + bb;
            float att = 1.f / (1.f + __expf(-t));
            acc2[ct][e] = hv[ct][e] * att;   // g >= 0
        }
    }

    // ---- segment reduction (batch sorted) ----
    int seg_lo = batch[base];
    int seg_hi = batch[base + 63];
    seg_lo = seg_lo < 0 ? 0 : (seg_lo > 511 ? 511 : seg_lo);
    seg_hi = seg_hi < 0 ? 0 : (seg_hi > 511 ? 511 : seg_hi);
    const int span = seg_hi - seg_lo + 1;

    if (span >= 1 && span <= NSLOT) {
        const int sw_lo = batch[r0];
        const int sw_hi = batch[r0 + 15];
        if (sw_lo == sw_hi) {
            // wave-uniform segment: register + shuffle reduce, 1 LDS atomic pair per col
            const int slot = sw_lo - seg_lo;
#pragma unroll
            for (int ct = 0; ct < 16; ++ct) {
                float s = acc2[ct][0] + acc2[ct][1] + acc2[ct][2] + acc2[ct][3];
                float m = fmaxf(fmaxf(acc2[ct][0], acc2[ct][1]), fmaxf(acc2[ct][2], acc2[ct][3]));
                s += __shfl_xor(s, 16, 64);
                s += __shfl_xor(s, 32, 64);
                m = fmaxf(m, __shfl_xor(m, 16, 64));
                m = fmaxf(m, __shfl_xor(m, 32, 64));
                if (q == 0) {
                    atomicAdd(&bsum[slot][ct * 16 + r], s);
                    atomicMax(&bmax[slot][ct * 16 + r], __float_as_uint(m));
                }
            }
        } else {
            // boundary wave: per-row LDS atomics
            int slot_e[4];
#pragma unroll
            for (int e = 0; e < 4; ++e) slot_e[e] = batch[r0 + q * 4 + e] - seg_lo;
#pragma unroll
            for (int ct = 0; ct < 16; ++ct) {
                const int c = ct * 16 + r;
#pragma unroll
                for (int e = 0; e < 4; ++e) {
                    float v = acc2[ct][e];
                    atomicAdd(&bsum[slot_e[e]][c], v);
                    atomicMax(&bmax[slot_e[e]][c], __float_as_uint(v));
                }
            }
        }
    } else {
        // pathological span (shouldn't happen with ~390 rows/segment): direct global atomics
#pragma unroll
        for (int ct = 0; ct < 16; ++ct) {
            const int c = ct * 16 + r;
#pragma unroll
            for (int e = 0; e < 4; ++e) {
                int sg = batch[r0 + q * 4 + e];
                sg = sg < 0 ? 0 : (sg > 511 ? 511 : sg);
                float v = acc2[ct][e];
                atomicAdd(&out[(size_t)sg * 512 + 256 + c], v);
                atomicMax((unsigned int*)&out[(size_t)sg * 512 + c], __float_as_uint(v));
            }
        }
    }

    // counts (one per row)
    if (tid < 64) {
        int sg = batch[base + tid];
        sg = sg < 0 ? 0 : (sg > 511 ? 511 : sg);
        atomicAdd(&counts[sg], 1);
    }

    __syncthreads();
    if (span >= 1 && span <= NSLOT) {
        // drain block slots to global: out[seg][0:256]=max bits, out[seg][256:512]=sum
        for (int s = 0; s < span; ++s) {
            const int seg = seg_lo + s;
            float        sv = bsum[s][tid];
            unsigned int mv = bmax[s][tid];
            if (sv != 0.0f) atomicAdd(&out[(size_t)seg * 512 + 256 + tid], sv);
            if (mv != 0u)   atomicMax((unsigned int*)&out[(size_t)seg * 512 + tid], mv);
        }
    }
}

__global__ void finalize_kernel(float* __restrict__ out, const int* __restrict__ counts) {
    const int b = blockIdx.x;
    const int c = threadIdx.x;
    const int cnt = counts[b];
    float s = out[(size_t)b * 512 + 256 + c];
    out[(size_t)b * 512 + 256 + c] = cnt > 0 ? s / (float)cnt : 0.0f;
    // max half already holds valid float bits (or 0 for empty segments)
}

extern "C" void kernel_launch(void* const* d_in, const int* in_sizes, int n_in,
                              void* d_out, int out_size, void* d_ws, size_t ws_size,
                              hipStream_t stream) {
    const float* x     = (const float*)d_in[0];
    const int*   batch = (const int*)d_in[1];
    const float* W1    = (const float*)d_in[2];
    const float* b1    = (const float*)d_in[3];
    const float* W2    = (const float*)d_in[4];
    const float* b2    = (const float*)d_in[5];
    float* out = (float*)d_out;

    unsigned short* W1b    = (unsigned short*)d_ws;
    unsigned short* W2b    = W1b + 65536;
    int*            counts = (int*)(W2b + 65536);

    const int Nrows  = in_sizes[0] / H;   // 200000
    const int blocks = Nrows / 64;        // 3125 (exact)

    hipMemsetAsync(d_out, 0, (size_t)out_size * sizeof(float), stream);
    hipMemsetAsync(counts, 0, 512 * sizeof(int), stream);
    conv_w_kernel<<<256, 256, 0, stream>>>(W1, W2, W1b, W2b);
    fused_main<<<blocks, 256, 0, stream>>>(x, batch, W1b, b1, W2b, b2, out, counts);
    finalize_kernel<<<512, 256, 0, stream>>>(out, counts);
}

// Round 2
// 673.529 us; speedup vs baseline: 1.3867x; 1.3867x over previous
//
#include <hip/hip_runtime.h>

#define H 256
#define NSLOT 4

typedef short bf16x8 __attribute__((ext_vector_type(8)));
typedef float f32x4  __attribute__((ext_vector_type(4)));

__device__ __forceinline__ unsigned int f2bf(float f) {
    unsigned int u = __float_as_uint(f);
    return (u + 0x7fffu + ((u >> 16) & 1u)) >> 16;   // RNE to bf16
}

__global__ void conv_w_kernel(const float* __restrict__ W1, const float* __restrict__ W2,
                              unsigned short* __restrict__ W1b, unsigned short* __restrict__ W2b) {
    int i = blockIdx.x * 256 + threadIdx.x;           // 256 blocks x 256 = 65536
    W1b[i] = (unsigned short)f2bf(W1[i]);
    W2b[i] = (unsigned short)f2bf(W2[i]);
}

// 4 waves/block, 16 rows/wave, 64 rows/block. MFMA 16x16x32 bf16.
// A layout: A[m=lane&15][k=quad*8+j]; B layout: B[k=quad*8+j][n=lane&15];
// C/D: col=lane&15, row=quad*4+reg.   (verified passing in R1)
// W is staged through LDS in 4 chunks of 64 W-rows (32 KB) per GEMM.
__global__ __launch_bounds__(256, 2) void fused_main(
    const float* __restrict__ x, const int* __restrict__ batch,
    const unsigned short* __restrict__ W1b, const float* __restrict__ b1,
    const unsigned short* __restrict__ W2b, const float* __restrict__ b2,
    float* __restrict__ out, int* __restrict__ counts)
{
    // 264 = 256 + 8 pad shorts -> 528B row stride (mod 128 = 16) keeps b128
    // reads/writes at the 8-phase minimum.
    __shared__ __align__(16) unsigned short Wl[64][264];        // 33792 B
    __shared__ __align__(16) unsigned short hlds[4][16][264];   // 33792 B
    __shared__ float        bsum[NSLOT][H];                     // 4096 B
    __shared__ unsigned int bmax[NSLOT][H];                     // 4096 B
    // total 75776 B -> 2 blocks/CU

    const int tid  = threadIdx.x;
    const int wave = tid >> 6;
    const int lane = tid & 63;
    const int r    = lane & 15;   // m / n index
    const int q    = lane >> 4;   // quad
    const int base = blockIdx.x * 64;
    const int r0   = base + wave * 16;

    for (int i = tid; i < NSLOT * H; i += 256) {
        (&bsum[0][0])[i] = 0.0f;
        (&bmax[0][0])[i] = 0u;
    }

    // ---- A1 fragments: x rows, fp32 -> bf16 in regs (32 VGPRs) ----
    bf16x8 a1[8];
    {
        const float* xrow = x + (size_t)(r0 + r) * H;
#pragma unroll
        for (int kk = 0; kk < 8; ++kk) {
            const int k0 = kk * 32 + q * 8;
            const float4 lo = *(const float4*)(xrow + k0);
            const float4 hi = *(const float4*)(xrow + k0 + 4);
            bf16x8 af;
            af[0] = (short)f2bf(lo.x); af[1] = (short)f2bf(lo.y);
            af[2] = (short)f2bf(lo.z); af[3] = (short)f2bf(lo.w);
            af[4] = (short)f2bf(hi.x); af[5] = (short)f2bf(hi.y);
            af[6] = (short)f2bf(hi.z); af[7] = (short)f2bf(hi.w);
            a1[kk] = af;
        }
    }

    // ---- segment bookkeeping (batch sorted) ----
    int sl = batch[base];       sl = sl < 0 ? 0 : (sl > 511 ? 511 : sl);
    int sh = batch[base + 63];  sh = sh < 0 ? 0 : (sh > 511 ? 511 : sh);
    const int  seg_lo     = sl;
    const int  span       = sh - sl + 1;
    const bool small_span = (span >= 1 && span <= NSLOT);
    const bool uni        = (batch[r0] == batch[r0 + 15]);   // wave-uniform
    const int  uslot      = batch[r0] - seg_lo;
    int slot_e[4];
#pragma unroll
    for (int e = 0; e < 4; ++e) slot_e[e] = batch[r0 + q * 4 + e] - seg_lo;

    f32x4 hv[16];   // fp32 h kept for the gate (64 VGPRs)

    // ================= GEMM1: h = relu(x @ W1^T + b1) =================
#pragma unroll
    for (int c = 0; c < 4; ++c) {
        // stage W1 rows [c*64, c*64+64) -> Wl  (coalesced 16B loads, padded LDS)
        const bf16x8* src = (const bf16x8*)(W1b + (size_t)c * 64 * H);
#pragma unroll
        for (int i = 0; i < 8; ++i) {
            const int g = tid + i * 256;
            bf16x8 v = src[g];
            *(bf16x8*)&Wl[g >> 5][(g & 31) * 8] = v;
        }
        __syncthreads();

#pragma unroll
        for (int ctl = 0; ctl < 4; ++ctl) {
            const int cg = c * 4 + ctl;
            f32x4 a = (f32x4){0.f, 0.f, 0.f, 0.f};
#pragma unroll
            for (int kk = 0; kk < 8; ++kk) {
                bf16x8 bfr = *(const bf16x8*)&Wl[ctl * 16 + r][kk * 32 + q * 8];
                a = __builtin_amdgcn_mfma_f32_16x16x32_bf16(a1[kk], bfr, a, 0, 0, 0);
            }
            const float bb = b1[cg * 16 + r];
#pragma unroll
            for (int e = 0; e < 4; ++e) {
                float h = a[e] + bb;
                h = h > 0.f ? h : 0.f;
                hv[cg][e] = h;
                hlds[wave][q * 4 + e][cg * 16 + r] = (unsigned short)f2bf(h);
            }
        }
        __syncthreads();   // chunk's readers done before next overwrite (also orders hlds)
    }

    // ---- A2 fragments from hlds (own wave's 16 rows) ----
    bf16x8 a2[8];
#pragma unroll
    for (int kk = 0; kk < 8; ++kk)
        a2[kk] = *(const bf16x8*)&hlds[wave][r][kk * 32 + q * 8];

    // ========= GEMM2: att = sigmoid(h @ W2^T + b2); g = h*att; reduce =========
#pragma unroll
    for (int c = 0; c < 4; ++c) {
        const bf16x8* src = (const bf16x8*)(W2b + (size_t)c * 64 * H);
#pragma unroll
        for (int i = 0; i < 8; ++i) {
            const int g = tid + i * 256;
            bf16x8 v = src[g];
            *(bf16x8*)&Wl[g >> 5][(g & 31) * 8] = v;
        }
        __syncthreads();

#pragma unroll
        for (int ctl = 0; ctl < 4; ++ctl) {
            const int cg = c * 4 + ctl;
            f32x4 a = (f32x4){0.f, 0.f, 0.f, 0.f};
#pragma unroll
            for (int kk = 0; kk < 8; ++kk) {
                bf16x8 bfr = *(const bf16x8*)&Wl[ctl * 16 + r][kk * 32 + q * 8];
                a = __builtin_amdgcn_mfma_f32_16x16x32_bf16(a2[kk], bfr, a, 0, 0, 0);
            }
            const float bb = b2[cg * 16 + r];
            float g4[4];
#pragma unroll
            for (int e = 0; e < 4; ++e) {
                float t   = a[e] + bb;
                float att = 1.f / (1.f + __expf(-t));
                g4[e] = hv[cg][e] * att;   // g >= 0
            }

            const int col = cg * 16 + r;
            if (small_span) {
                if (uni) {
                    float s = g4[0] + g4[1] + g4[2] + g4[3];
                    float m = fmaxf(fmaxf(g4[0], g4[1]), fmaxf(g4[2], g4[3]));
                    s += __shfl_xor(s, 16, 64);
                    s += __shfl_xor(s, 32, 64);
                    m = fmaxf(m, __shfl_xor(m, 16, 64));
                    m = fmaxf(m, __shfl_xor(m, 32, 64));
                    if (q == 0) {
                        atomicAdd(&bsum[uslot][col], s);
                        atomicMax(&bmax[uslot][col], __float_as_uint(m));
                    }
                } else {
#pragma unroll
                    for (int e = 0; e < 4; ++e) {
                        atomicAdd(&bsum[slot_e[e]][col], g4[e]);
                        atomicMax(&bmax[slot_e[e]][col], __float_as_uint(g4[e]));
                    }
                }
            } else {
                // pathological span: direct global atomics
#pragma unroll
                for (int e = 0; e < 4; ++e) {
                    int sg = batch[r0 + q * 4 + e];
                    sg = sg < 0 ? 0 : (sg > 511 ? 511 : sg);
                    atomicAdd(&out[(size_t)sg * 512 + 256 + col], g4[e]);
                    atomicMax((unsigned int*)&out[(size_t)sg * 512 + col], __float_as_uint(g4[e]));
                }
            }
        }
        __syncthreads();
    }

    // counts (one per row)
    if (tid < 64) {
        int sg = batch[base + tid];
        sg = sg < 0 ? 0 : (sg > 511 ? 511 : sg);
        atomicAdd(&counts[sg], 1);
    }

    // drain block slots (last chunk's closing barrier already ordered bsum/bmax)
    if (small_span) {
        for (int s = 0; s < span; ++s) {
            const int seg = seg_lo + s;
            float        sv = bsum[s][tid];
            unsigned int mv = bmax[s][tid];
            if (sv != 0.0f) atomicAdd(&out[(size_t)seg * 512 + 256 + tid], sv);
            if (mv != 0u)   atomicMax((unsigned int*)&out[(size_t)seg * 512 + tid], mv);
        }
    }
}

__global__ void finalize_kernel(float* __restrict__ out, const int* __restrict__ counts) {
    const int b = blockIdx.x;
    const int c = threadIdx.x;
    const int cnt = counts[b];
    float s = out[(size_t)b * 512 + 256 + c];
    out[(size_t)b * 512 + 256 + c] = cnt > 0 ? s / (float)cnt : 0.0f;
}

extern "C" void kernel_launch(void* const* d_in, const int* in_sizes, int n_in,
                              void* d_out, int out_size, void* d_ws, size_t ws_size,
                              hipStream_t stream) {
    const float* x     = (const float*)d_in[0];
    const int*   batch = (const int*)d_in[1];
    const float* W1    = (const float*)d_in[2];
    const float* b1    = (const float*)d_in[3];
    const float* W2    = (const float*)d_in[4];
    const float* b2    = (const float*)d_in[5];
    float* out = (float*)d_out;

    unsigned short* W1b    = (unsigned short*)d_ws;
    unsigned short* W2b    = W1b + 65536;
    int*            counts = (int*)(W2b + 65536);

    const int Nrows  = in_sizes[0] / H;   // 200000
    const int blocks = Nrows / 64;        // 3125 (exact)

    hipMemsetAsync(d_out, 0, (size_t)out_size * sizeof(float), stream);
    hipMemsetAsync(counts, 0, 512 * sizeof(int), stream);
    conv_w_kernel<<<256, 256, 0, stream>>>(W1, W2, W1b, W2b);
    fused_main<<<blocks, 256, 0, stream>>>(x, batch, W1b, b1, W2b, b2, out, counts);
    finalize_kernel<<<512, 256, 0, stream>>>(out, counts);
}